// Round 1
// baseline (335.953 us; speedup 1.0000x reference)
//
#include <hip/hip_runtime.h>

typedef __bf16 bf16_t;
typedef __attribute__((ext_vector_type(8))) __bf16 bf16x8;
typedef __attribute__((ext_vector_type(4))) float f32x4;

constexpr int Bc = 4, Sc = 2048, Dc = 512, Hc = 4, HDc = 128;
constexpr int Mrows = Bc * Sc;  // 8192

// ---------- weight transpose + cast: dst[n*K+k] = bf16(src[k*N+n]) ----------
__global__ __launch_bounds__(256) void wt_transpose_k(const float* __restrict__ src,
                                                      bf16_t* __restrict__ dst,
                                                      int K, int N) {
  __shared__ float tile[32][33];
  const int tx = threadIdx.x & 31, ty = threadIdx.x >> 5;
  const int n0 = blockIdx.x * 32, k0 = blockIdx.y * 32;
#pragma unroll
  for (int i = 0; i < 4; i++)
    tile[ty + i * 8][tx] = src[(long)(k0 + ty + i * 8) * N + n0 + tx];
  __syncthreads();
#pragma unroll
  for (int i = 0; i < 4; i++)
    dst[(long)(n0 + ty + i * 8) * K + k0 + tx] = (bf16_t)tile[tx][ty + i * 8];
}

// ---------- MFMA GEMM: C[M,N] = A[M,K] @ Bt[N,K]^T + bias, fused epilogues ----
// AMODE: 0 = A fp32 (convert in staging), 1 = A bf16
// OMODE: 0 = relu -> bf16 row-major ; 1 = fp32 row-major ; 2 = qkv scatter bf16
template <int AMODE, int OMODE>
__global__ __launch_bounds__(256, 4) void gemm_k(
    const void* __restrict__ Ap, const bf16_t* __restrict__ Bt,
    const float* __restrict__ bias0, const float* __restrict__ bias1,
    const float* __restrict__ bias2, void* __restrict__ out0,
    void* __restrict__ out1, void* __restrict__ out2, int N, int K, int lda) {
  __shared__ bf16_t As[64][40];   // [m][k], pad 40 to spread banks, 16B-aligned rows
  __shared__ bf16_t Bs[64][40];   // [n][k]
  const int t = threadIdx.x;
  const int n0 = blockIdx.x * 64, m0 = blockIdx.y * 64;
  const int lane = t & 63, wave = t >> 6;
  const int quad = lane >> 4, ln = lane & 15;
  const int wm = wave >> 1, wn = wave & 1;
  f32x4 acc[2][2] = {};
  for (int k0 = 0; k0 < K; k0 += 32) {
    if constexpr (AMODE == 0) {
      const float* A = (const float*)Ap;
#pragma unroll
      for (int i = 0; i < 2; i++) {
        const int f = t + i * 256;
        const int r = f >> 3, c4 = (f & 7) * 4;
        const float4 va = *(const float4*)(A + (long)(m0 + r) * lda + k0 + c4);
        bf16_t* d = &As[r][c4];
        d[0] = (bf16_t)va.x; d[1] = (bf16_t)va.y;
        d[2] = (bf16_t)va.z; d[3] = (bf16_t)va.w;
      }
    } else {
      const bf16_t* A = (const bf16_t*)Ap;
      const int r = t >> 2, c8 = (t & 3) * 8;
      *(uint4*)&As[r][c8] = *(const uint4*)(A + (long)(m0 + r) * lda + k0 + c8);
    }
    {
      const int r = t >> 2, c8 = (t & 3) * 8;
      *(uint4*)&Bs[r][c8] = *(const uint4*)(Bt + (long)(n0 + r) * K + k0 + c8);
    }
    __syncthreads();
    bf16x8 af[2], bfr[2];
#pragma unroll
    for (int mt = 0; mt < 2; mt++)
      af[mt] = *(const bf16x8*)&As[wm * 32 + mt * 16 + ln][quad * 8];
#pragma unroll
    for (int nt = 0; nt < 2; nt++)
      bfr[nt] = *(const bf16x8*)&Bs[wn * 32 + nt * 16 + ln][quad * 8];
#pragma unroll
    for (int mt = 0; mt < 2; mt++)
#pragma unroll
      for (int nt = 0; nt < 2; nt++)
        acc[mt][nt] = __builtin_amdgcn_mfma_f32_16x16x32_bf16(af[mt], bfr[nt],
                                                              acc[mt][nt], 0, 0, 0);
    __syncthreads();
  }
#pragma unroll
  for (int mt = 0; mt < 2; mt++)
#pragma unroll
    for (int nt = 0; nt < 2; nt++)
#pragma unroll
      for (int r = 0; r < 4; r++) {
        const int grow = m0 + wm * 32 + mt * 16 + quad * 4 + r;
        const int gcol = n0 + wn * 32 + nt * 16 + ln;
        float vv = acc[mt][nt][r];
        if constexpr (OMODE == 0) {
          vv += bias0[gcol];
          vv = vv > 0.f ? vv : 0.f;
          ((bf16_t*)out0)[(long)grow * N + gcol] = (bf16_t)vv;
        } else if constexpr (OMODE == 1) {
          vv += bias0[gcol];
          ((float*)out0)[(long)grow * N + gcol] = vv;
        } else {
          const int which = gcol >> 9, n = gcol & 511;
          const int hh = n >> 7, hd = n & 127;
          const int b = grow >> 11, s = grow & 2047;
          const float* bias = which == 0 ? bias0 : (which == 1 ? bias1 : bias2);
          vv += bias[n];
          bf16_t* o = (bf16_t*)(which == 0 ? out0 : (which == 1 ? out1 : out2));
          long idx;
          if (which == 2)  // v stored transposed [b,h,hd,s]
            idx = ((long)(b * Hc + hh) * HDc + hd) * Sc + s;
          else             // q,k stored [b,h,s,hd]
            idx = ((long)(b * Hc + hh) * Sc + s) * HDc + hd;
          o[idx] = (bf16_t)vv;
        }
      }
}

// ---------- LayerNorm(xa + xb): one wave per row of 512 ----------
__global__ __launch_bounds__(256) void ln_k(const float* __restrict__ xa,
                                            const float* __restrict__ xb,
                                            const float* __restrict__ gamma,
                                            const float* __restrict__ beta,
                                            float* __restrict__ out) {
  const int wave = threadIdx.x >> 6, lane = threadIdx.x & 63;
  const long row = (long)blockIdx.x * 4 + wave;
  const float* a = xa + row * Dc;
  const float* b = xb + row * Dc;
  float v[8];
  float s = 0.f, s2 = 0.f;
#pragma unroll
  for (int i = 0; i < 2; i++) {
    const float4 va = *(const float4*)(a + lane * 4 + i * 256);
    const float4 vb = *(const float4*)(b + lane * 4 + i * 256);
    const float t0 = va.x + vb.x, t1 = va.y + vb.y;
    const float t2 = va.z + vb.z, t3 = va.w + vb.w;
    v[i * 4 + 0] = t0; v[i * 4 + 1] = t1; v[i * 4 + 2] = t2; v[i * 4 + 3] = t3;
    s += t0 + t1 + t2 + t3;
    s2 += t0 * t0 + t1 * t1 + t2 * t2 + t3 * t3;
  }
#pragma unroll
  for (int off = 1; off < 64; off <<= 1) {
    s += __shfl_xor(s, off, 64);
    s2 += __shfl_xor(s2, off, 64);
  }
  const float mu = s * (1.f / Dc);
  const float var = s2 * (1.f / Dc) - mu * mu;
  const float rstd = rsqrtf(var + 1e-5f);
#pragma unroll
  for (int i = 0; i < 2; i++)
#pragma unroll
    for (int j = 0; j < 4; j++) {
      const int col = lane * 4 + i * 256 + j;
      out[row * Dc + col] = (v[i * 4 + j] - mu) * rstd * gamma[col] + beta[col];
    }
}

// ---------- flash attention with distance bias ----------
// q,k: bf16 [b,h,s,hd]; v: bf16 [b,h,hd,s]; out ctx: fp32 [b,s,h*HD+hd]
__global__ __launch_bounds__(256, 2) void attn_k(const bf16_t* __restrict__ q,
                                                 const bf16_t* __restrict__ k,
                                                 const bf16_t* __restrict__ v,
                                                 const float* __restrict__ pos,
                                                 const float* __restrict__ alphap,
                                                 float* __restrict__ ctx) {
  __shared__ bf16_t Qs[64][136];   // [q][hd]   (272B rows, 16B aligned)
  __shared__ bf16_t Ks[64][136];   // [key][hd]
  __shared__ bf16_t Vts[128][72];  // [hd][key] (144B rows)
  __shared__ bf16_t Ps[4][16][72]; // per-wave P: [qrow][key]
  __shared__ float pq[64][4];      // x,y,z,|p|^2
  __shared__ float pk[64][4];
  const int t = threadIdx.x;
  const int qt = blockIdx.x, h = blockIdx.y, b = blockIdx.z;
  const int q0 = qt * 64;
  const int wave = t >> 6, lane = t & 63, quad = lane >> 4, ln = lane & 15;
  const float alpha = alphap[0];
  const float scale = 0.08838834764831845f;  // 1/sqrt(128)
  const bf16_t* qbase = q + ((long)(b * Hc + h) * Sc + q0) * HDc;
  const bf16_t* kbase = k + (long)(b * Hc + h) * Sc * HDc;
  const bf16_t* vbase = v + (long)(b * Hc + h) * HDc * Sc;

#pragma unroll
  for (int i = 0; i < 4; i++) {  // Q tile: 64x128 bf16 = 1024 uint4
    const int f = t + i * 256;
    const int r = f >> 4, c8 = (f & 15) * 8;
    *(uint4*)&Qs[r][c8] = *(const uint4*)(qbase + (long)r * HDc + c8);
  }
  if (t < 64) {
    const float x = pos[((long)b * Sc + q0 + t) * 3 + 0];
    const float y = pos[((long)b * Sc + q0 + t) * 3 + 1];
    const float z = pos[((long)b * Sc + q0 + t) * 3 + 2];
    pq[t][0] = x; pq[t][1] = y; pq[t][2] = z; pq[t][3] = x * x + y * y + z * z;
  }
  float m_i[4], l_i[4];
#pragma unroll
  for (int r = 0; r < 4; r++) { m_i[r] = -1e30f; l_i[r] = 0.f; }
  f32x4 acc_o[8] = {};

  for (int kt = 0; kt < Sc / 64; kt++) {
    __syncthreads();  // previous iteration's readers done (also covers Q staging)
#pragma unroll
    for (int i = 0; i < 4; i++) {  // K tile 64x128
      const int f = t + i * 256;
      const int r = f >> 4, c8 = (f & 15) * 8;
      *(uint4*)&Ks[r][c8] = *(const uint4*)(kbase + (long)(kt * 64 + r) * HDc + c8);
    }
#pragma unroll
    for (int i = 0; i < 4; i++) {  // V^T tile 128x64
      const int f = t + i * 256;
      const int hd = f >> 3, c8 = (f & 7) * 8;
      *(uint4*)&Vts[hd][c8] = *(const uint4*)(vbase + (long)hd * Sc + kt * 64 + c8);
    }
    if (t < 64) {
      const float x = pos[((long)b * Sc + kt * 64 + t) * 3 + 0];
      const float y = pos[((long)b * Sc + kt * 64 + t) * 3 + 1];
      const float z = pos[((long)b * Sc + kt * 64 + t) * 3 + 2];
      pk[t][0] = x; pk[t][1] = y; pk[t][2] = z; pk[t][3] = x * x + y * y + z * z;
    }
    __syncthreads();

    // S = Q @ K^T : wave handles 16 q-rows x 64 keys
    f32x4 sacc[4] = {};
#pragma unroll
    for (int kc = 0; kc < 4; kc++) {
      const bf16x8 af = *(const bf16x8*)&Qs[wave * 16 + ln][kc * 32 + quad * 8];
#pragma unroll
      for (int ct = 0; ct < 4; ct++) {
        const bf16x8 bfv = *(const bf16x8*)&Ks[ct * 16 + ln][kc * 32 + quad * 8];
        sacc[ct] = __builtin_amdgcn_mfma_f32_16x16x32_bf16(af, bfv, sacc[ct], 0, 0, 0);
      }
    }
    // bias + online softmax (C-layout: row = quad*4+r, col = ct*16+ln)
    float pvals[4][4], mx[4];
#pragma unroll
    for (int r = 0; r < 4; r++) mx[r] = -1e30f;
#pragma unroll
    for (int ct = 0; ct < 4; ct++) {
      const int kk = ct * 16 + ln;
      const float px = pk[kk][0], py = pk[kk][1], pz = pk[kk][2], pn = pk[kk][3];
#pragma unroll
      for (int r = 0; r < 4; r++) {
        const int qrow = wave * 16 + quad * 4 + r;
        float d2 = pq[qrow][3] + pn -
                   2.f * (pq[qrow][0] * px + pq[qrow][1] * py + pq[qrow][2] * pz);
        d2 = d2 > 0.f ? d2 : 0.f;
        const float sv = sacc[ct][r] * scale - alpha * d2;
        pvals[ct][r] = sv;
        mx[r] = fmaxf(mx[r], sv);
      }
    }
#pragma unroll
    for (int off = 1; off < 16; off <<= 1)
#pragma unroll
      for (int r = 0; r < 4; r++) mx[r] = fmaxf(mx[r], __shfl_xor(mx[r], off, 64));
    float rs[4], sf[4];
#pragma unroll
    for (int r = 0; r < 4; r++) {
      const float mnew = fmaxf(m_i[r], mx[r]);
      sf[r] = __expf(m_i[r] - mnew);
      m_i[r] = mnew;
      rs[r] = 0.f;
    }
#pragma unroll
    for (int ct = 0; ct < 4; ct++)
#pragma unroll
      for (int r = 0; r < 4; r++) {
        const float p = __expf(pvals[ct][r] - m_i[r]);
        pvals[ct][r] = p;
        rs[r] += p;
      }
#pragma unroll
    for (int off = 1; off < 16; off <<= 1)
#pragma unroll
      for (int r = 0; r < 4; r++) rs[r] += __shfl_xor(rs[r], off, 64);
#pragma unroll
    for (int r = 0; r < 4; r++) l_i[r] = l_i[r] * sf[r] + rs[r];
#pragma unroll
    for (int nt = 0; nt < 8; nt++)
#pragma unroll
      for (int r = 0; r < 4; r++) acc_o[nt][r] *= sf[r];
    // P: C-layout -> LDS -> A-layout
#pragma unroll
    for (int ct = 0; ct < 4; ct++)
#pragma unroll
      for (int r = 0; r < 4; r++)
        Ps[wave][quad * 4 + r][ct * 16 + ln] = (bf16_t)pvals[ct][r];
    __syncthreads();
    // O += P @ V
#pragma unroll
    for (int s2 = 0; s2 < 2; s2++) {
      const bf16x8 pf = *(const bf16x8*)&Ps[wave][ln][s2 * 32 + quad * 8];
#pragma unroll
      for (int nt = 0; nt < 8; nt++) {
        const bf16x8 vf = *(const bf16x8*)&Vts[nt * 16 + ln][s2 * 32 + quad * 8];
        acc_o[nt] = __builtin_amdgcn_mfma_f32_16x16x32_bf16(pf, vf, acc_o[nt], 0, 0, 0);
      }
    }
  }
#pragma unroll
  for (int nt = 0; nt < 8; nt++)
#pragma unroll
    for (int r = 0; r < 4; r++) {
      const int qrow = wave * 16 + quad * 4 + r;
      const float o = acc_o[nt][r] / l_i[r];
      ctx[((long)b * Sc + q0 + qrow) * Dc + h * HDc + nt * 16 + ln] = o;
    }
}

// ---------------- workspace layout (bytes) ----------------
constexpr size_t SE_OFF = 0;                          // fp32 8192x512
constexpr size_t CTX_OFF = 16777216;                  // fp32 8192x512 (also sq)
constexpr size_t Q_OFF = 2u * 16777216;               // bf16 8192x512 (h aliases q..k)
constexpr size_t K_OFF = Q_OFF + 8388608;
constexpr size_t V_OFF = K_OFF + 8388608;
constexpr size_t WTE_OFF = V_OFF + 8388608;           // bf16 1024x512
constexpr size_t WTS_OFF = WTE_OFF + 1048576;         // bf16 512x1024
constexpr size_t WTQKV_OFF = WTS_OFF + 1048576;       // bf16 1536x512
// total = WTQKV_OFF + 1572864 = 62,390,272 bytes

extern "C" void kernel_launch(void* const* d_in, const int* in_sizes, int n_in,
                              void* d_out, int out_size, void* d_ws, size_t ws_size,
                              hipStream_t stream) {
  const float* X = (const float*)d_in[0];
  const float* pos = (const float*)d_in[1];
  const float* W_expand = (const float*)d_in[2];
  const float* b_expand = (const float*)d_in[3];
  const float* W_squeeze = (const float*)d_in[4];
  const float* b_squeeze = (const float*)d_in[5];
  const float* gamma = (const float*)d_in[6];
  const float* beta = (const float*)d_in[7];
  const float* Wq = (const float*)d_in[8];
  const float* bq = (const float*)d_in[9];
  const float* Wk = (const float*)d_in[10];
  const float* bk = (const float*)d_in[11];
  const float* Wv = (const float*)d_in[12];
  const float* bv = (const float*)d_in[13];
  const float* alphap = (const float*)d_in[14];

  char* ws = (char*)d_ws;
  float* se = (float*)(ws + SE_OFF);
  float* sq = (float*)(ws + CTX_OFF);  // squeeze output, later ctx
  bf16_t* qb = (bf16_t*)(ws + Q_OFF);
  bf16_t* kb = (bf16_t*)(ws + K_OFF);
  bf16_t* vb = (bf16_t*)(ws + V_OFF);
  bf16_t* hb = (bf16_t*)(ws + Q_OFF);  // 8192x1024 bf16, dead before q/k written
  bf16_t* wtE = (bf16_t*)(ws + WTE_OFF);
  bf16_t* wtS = (bf16_t*)(ws + WTS_OFF);
  bf16_t* wtQKV = (bf16_t*)(ws + WTQKV_OFF);

  // weights -> bf16 B^T
  wt_transpose_k<<<dim3(1024 / 32, 512 / 32), 256, 0, stream>>>(W_expand, wtE, 512, 1024);
  wt_transpose_k<<<dim3(512 / 32, 1024 / 32), 256, 0, stream>>>(W_squeeze, wtS, 1024, 512);
  wt_transpose_k<<<dim3(16, 16), 256, 0, stream>>>(Wq, wtQKV, 512, 512);
  wt_transpose_k<<<dim3(16, 16), 256, 0, stream>>>(Wk, wtQKV + 512 * 512, 512, 512);
  wt_transpose_k<<<dim3(16, 16), 256, 0, stream>>>(Wv, wtQKV + 2 * 512 * 512, 512, 512);

  // h = relu(X @ We + be)            [8192,1024] bf16
  gemm_k<0, 0><<<dim3(1024 / 64, Mrows / 64), 256, 0, stream>>>(
      X, wtE, b_expand, nullptr, nullptr, hb, nullptr, nullptr, 1024, 512, 512);
  // sq = h @ Ws + bs                 [8192,512] fp32
  gemm_k<1, 1><<<dim3(512 / 64, Mrows / 64), 256, 0, stream>>>(
      hb, wtS, b_squeeze, nullptr, nullptr, sq, nullptr, nullptr, 512, 1024, 1024);
  // se = LN(X + sq)
  ln_k<<<Mrows / 4, 256, 0, stream>>>(X, sq, gamma, beta, se);
  // q,k,v = se @ [Wq|Wk|Wv] + b      scattered bf16
  gemm_k<0, 2><<<dim3(1536 / 64, Mrows / 64), 256, 0, stream>>>(
      se, wtQKV, bq, bk, bv, qb, kb, vb, 1536, 512, 512);
  // ctx = attention(q,k,v,pos)       [8192,512] fp32 (reuses sq buffer)
  attn_k<<<dim3(Sc / 64, Hc, Bc), 256, 0, stream>>>(qb, kb, vb, pos, alphap, sq);
  // out = LN(se + ctx)
  ln_k<<<Mrows / 4, 256, 0, stream>>>(se, sq, gamma, beta, (float*)d_out);

  (void)in_sizes; (void)n_in; (void)out_size; (void)ws_size;
}